// Round 14
// baseline (140.590 us; speedup 1.0000x reference)
//
#include <hip/hip_runtime.h>

// x (B,I); w/s/t (O,I); out (B,O), all fp32.
#define B_SZ 256
#define O_SZ 1024
#define I_SZ 1024

#define TB   4     // b rows per block (LDS x tile)
#define SLN  32    // lanes per half splitting i
#define KITERS (I_SZ / (SLN * 4))   // 8
#define ISTEP  (SLN * 4)            // 128
#define OITER  4                    // o-groups per block (32 o's/block)
#define OSTRIDE (8 * I_SZ)

typedef float v2f __attribute__((ext_vector_type(2)));

// out[b,o] = sum_i w[o,i]*phi((x[b,i]-t[o,i])/s[o,i]),  phi(z) = -z*exp(-0.5 z^2)
//
// TRANS-FREE math (R11 retry, done right): u = z*C (C=1/sqrt(32)), h = u^2 = z^2/32,
// clamp h<=0.8125 (|z|<=5.1; beyond, |phi|<1e-5*|w|), p = deg-4 Taylor of e^-h
// (rel err <=3e-3 at clamp edge), q = p^16 = e^(-z^2/2) (err amplif x16 lands on
// e^-13; max abs err ~2e-6 mid-range). y = u*w_raw; final scaled by 1/C once.
// 28 cyc/pair-step all on the full-rate v_pk_*_f32 pipe vs 40 with 2x v_exp_f32.
// R11's literal-scalarization trap avoided: non-inline Horner consts (1/24, -1/6)
// are KERNEL ARGS (SGPR); 0.5/-1/1 are VOP3P inline constants.
//
// Latency (R12/R13): w/s/t stream = 12 MB/pass > 4 MB per-XCD L2 -> warm L3 misses
// ~400+ cyc; depth-2 register prefetch (A/B sets) gives ~600 cyc cover. R13 spilled
// because (256,8) pinned the allocator at 32 VGPR; (256,4) relaxes it (R10: 44) and
// still allows 8 blocks/CU if the allocation lands <=64. Spill watch: WRITE_SIZE.
__device__ __forceinline__ int goff(int g) {
    g &= (8 * OITER - 1);                       // mod 32 steps
    return (g >> 3) * OSTRIDE + (g & 7) * ISTEP;
}

__launch_bounds__(256, 4)
__global__ void wavkan_dog_kernel(const float* __restrict__ X,
                                  const float* __restrict__ W,
                                  const float* __restrict__ S,
                                  const float* __restrict__ T,
                                  float* __restrict__ Out,
                                  float C, float iC, float PA, float PB, float Hc) {
    const int tid  = threadIdx.x;
    const int wave = tid >> 6;
    const int lane = tid & 63;
    const int half = lane >> 5;
    const int sl   = lane & (SLN - 1);

    const int obase = blockIdx.x * (8 * OITER) + wave * 2 + half; // + oi*8
    const int b0    = blockIdx.y * TB;

    __shared__ __align__(16) float xls[TB * I_SZ];     // 16 KB

    const int r0 = obase * I_SZ + sl * 4;
    const float* wr = W + r0;
    const float* sr = S + r0;
    const float* tr = T + r0;

    // depth-2 prefetch: steps g=0 (A) and g=1 (B), issued before the LDS fill
    float4 sA = *(const float4*)(sr);
    float4 tA = *(const float4*)(tr);
    float4 wA = *(const float4*)(wr);
    float4 sB = *(const float4*)(sr + ISTEP);
    float4 tB = *(const float4*)(tr + ISTEP);
    float4 wB = *(const float4*)(wr + ISTEP);

    {   // cooperative fill: x[b0:b0+4][:] is one contiguous 16 KB span
        const float4* Xg4 = (const float4*)(X + (size_t)b0 * I_SZ);
        float4* L4 = (float4*)xls;
#pragma unroll
        for (int p = 0; p < (TB * I_SZ / 4) / 256; ++p)
            L4[tid + p * 256] = Xg4[tid + p * 256];
    }
    __syncthreads();

    // broadcast poly constants (runtime args -> no literal folding)
    const v2f PAv = { PA, PA };     // 1/24
    const v2f PBv = { PB, PB };     // -1/6
    const v2f Hcv = { Hc, Hc };     // 0.8125
    const float* xb = xls + sl * 4;

#pragma unroll 1
    for (int oi = 0; oi < OITER; ++oi) {
        v2f acc[TB];
#pragma unroll
        for (int j = 0; j < TB; ++j) acc[j] = (v2f)(0.0f);

#pragma unroll 1
        for (int k = 0; k < KITERS; k += 2) {
            const int g = oi * 8 + k;

#pragma unroll
            for (int ph = 0; ph < 2; ++ph) {
                // consume buffer ph (step g+ph), prefetch step g+ph+2 into it
                const float4 s4 = ph ? sB : sA;
                const float4 t4 = ph ? tB : tA;
                const float4 w4 = ph ? wB : wA;
                const int pf = goff(g + ph + 2);
                if (ph) { sB = *(const float4*)(sr + pf);
                          tB = *(const float4*)(tr + pf);
                          wB = *(const float4*)(wr + pf); }
                else    { sA = *(const float4*)(sr + pf);
                          tA = *(const float4*)(tr + pf);
                          wA = *(const float4*)(wr + pf); }

                v2f rk[2], tkn[2], wv[2];
                {
                    const float* sa = (const float*)&s4;
                    const float* ta = (const float*)&t4;
                    const float* wa = (const float*)&w4;
#pragma unroll
                    for (int cp = 0; cp < 2; ++cp) {
                        const v2f r = { __builtin_amdgcn_rcpf(sa[2*cp]),
                                        __builtin_amdgcn_rcpf(sa[2*cp+1]) };
                        rk[cp]  = r * C;                               // C/s
                        tkn[cp] = -(v2f){ta[2*cp], ta[2*cp+1]} * rk[cp]; // -t*C/s
                        wv[cp]  = (v2f){wa[2*cp], wa[2*cp+1]};         // raw w
                    }
                }

                const int i = (k + ph) * ISTEP;
#pragma unroll
                for (int j = 0; j < TB; ++j) {
                    const float4 xv = *(const float4*)(xb + j * I_SZ + i); // ds_read_b128
                    const float* xp = (const float*)&xv;
#pragma unroll
                    for (int cp = 0; cp < 2; ++cp) {
                        const v2f x2 = { xp[2*cp], xp[2*cp+1] };
                        const v2f u  = __builtin_elementwise_fma(x2, rk[cp], tkn[cp]); // z*C
                        const v2f h0 = u * u;                                          // z^2/32
                        const v2f h  = __builtin_elementwise_min(h0, Hcv);             // clamp
                        v2f p = __builtin_elementwise_fma(h, PAv, PBv);    // h/24 - 1/6
                        p = __builtin_elementwise_fma(p, h, (v2f)(0.5f));  // inline const
                        p = __builtin_elementwise_fma(p, h, (v2f)(-1.0f));
                        p = __builtin_elementwise_fma(p, h, (v2f)(1.0f));  // ~exp(-h)
                        v2f q = p * p;  q = q * q;  q = q * q;  q = q * q; // p^16
                        const v2f y = u * wv[cp];                          // w*z*C
                        acc[j] = __builtin_elementwise_fma(-y, q, acc[j]); // += -w*z*C*e
                    }
                }
            }
        }

        // collapse pairs, reduce across the 32 i-split lanes
        float r[TB];
#pragma unroll
        for (int j = 0; j < TB; ++j) r[j] = acc[j].x + acc[j].y;
#pragma unroll
        for (int m = 1; m < SLN; m <<= 1)
#pragma unroll
            for (int j = 0; j < TB; ++j)
                r[j] += __shfl_xor(r[j], m, 64);

        if (sl < TB) {
            float v = 0.0f;
#pragma unroll
            for (int j = 0; j < TB; ++j)
                if (sl == j) v = r[j];
            Out[(size_t)(b0 + sl) * O_SZ + (obase + oi * 8)] = v * iC; // undo z*C scale
        }
    }
}

extern "C" void kernel_launch(void* const* d_in, const int* in_sizes, int n_in,
                              void* d_out, int out_size, void* d_ws, size_t ws_size,
                              hipStream_t stream) {
    const float* x = (const float*)d_in[0];   // (B, I)
    const float* w = (const float*)d_in[1];   // (O, I)
    const float* s = (const float*)d_in[2];   // (O, I)
    const float* t = (const float*)d_in[3];   // (O, I)
    float* out = (float*)d_out;               // (B, O)

    const float C  = 0.17677669529663688110f;   // 1/sqrt(32)
    const float iC = 5.65685424949238019521f;   // sqrt(32)
    const float PA = 0.04166666666666666667f;   // 1/24
    const float PB = -0.16666666666666666667f;  // -1/6
    const float Hc = 0.8125f;                   // clamp: z^2 <= 26

    dim3 grid(O_SZ / (8 * OITER), B_SZ / TB);   // (32, 64) = 2048 blocks
    wavkan_dog_kernel<<<grid, 256, 0, stream>>>(x, w, s, t, out, C, iC, PA, PB, Hc);
}

// Round 15
// 112.491 us; speedup vs baseline: 1.2498x; 1.2498x over previous
//
#include <hip/hip_runtime.h>

// x (B,I); w/s/t (O,I); out (B,O), all fp32.
#define B_SZ 256
#define O_SZ 1024
#define I_SZ 1024

#define TB   8     // b rows per block (LDS x tile, 32 KB)
#define SLN  32    // lanes per half splitting i
#define KITERS (I_SZ / (SLN * 4))   // 8
#define ISTEP  (SLN * 4)            // 128
#define OITER  4                    // o-groups per block (32 o's/block)
#define OSTRIDE (8 * I_SZ)          // element stride between o-groups

typedef float v2f __attribute__((ext_vector_type(2)));

// out[b,o] = sum_i w[o,i]*phi((x[b,i]-t[o,i])/s[o,i]),  phi(z) = -z*exp(-0.5 z^2)
// u = K*(x-t)/s, K = sqrt(0.5*log2 e) -> exp2(-u^2) = exp(-z^2/2);  w*z = u*w*(1/K)
// (1/K folded into the epilogue). fma/mul packed (v_pk_*_f32 — the all-VGPR 4-op
// pattern is the ONLY one clang reliably packs: R11/R14 poly chains scalarized,
// 156k busy cyc vs 85k). exp2 on trans pipe (~16 cyc/wave; VALUBusy includes it).
//
// Idle diagnosis (R10 61% duty, 39% stall): w/s/t = 12 MB/pass > 4 MB per-XCD L2
// -> warm L3 ~400 cyc; depth-1 prefetch under-covers. Depth-2 pipeline here:
//   phase A: coefB=convert(raw g+1); raw=load(g+2); compute(coefA)
//   phase B: coefA=convert(raw g+2); raw=load(g+3); compute(coefB)
// Live ~66 VGPR. (256,4) NOT (256,8): R13's identical pipeline spilled because
// (256,8) pinned the allocator at 32 VGPR. Spill watch: WRITE_SIZE ~1 MB, VGPR>=64.
__device__ __forceinline__ int goff(int g) {
    g &= (8 * OITER - 1);                       // mod 32 steps
    return (g >> 3) * OSTRIDE + (g & 7) * ISTEP;
}

struct Coef { v2f rk[2], tkn[2], wv[2]; };

__launch_bounds__(256, 4)
__global__ void wavkan_dog_kernel(const float* __restrict__ X,
                                  const float* __restrict__ W,
                                  const float* __restrict__ S,
                                  const float* __restrict__ T,
                                  float* __restrict__ Out) {
    const int tid  = threadIdx.x;
    const int wave = tid >> 6;
    const int lane = tid & 63;
    const int half = lane >> 5;
    const int sl   = lane & (SLN - 1);

    const int obase = blockIdx.x * (8 * OITER) + wave * 2 + half; // + oi*8
    const int b0    = blockIdx.y * TB;

    __shared__ __align__(16) float xls[TB * I_SZ];     // 32 KB

    const int r0 = obase * I_SZ + sl * 4;
    const float* wr = W + r0;
    const float* sr = S + r0;
    const float* tr = T + r0;

    const float K = 0.84932180028801904272f;   // sqrt(0.5 * log2 e)

    // raw in-flight buffer (one set) + two coef sets
    float4 sR = *(const float4*)(sr);          // step 0, issued before LDS fill
    float4 tR = *(const float4*)(tr);
    float4 wR = *(const float4*)(wr);

    {   // cooperative fill: x[b0:b0+8][:] is one contiguous 32 KB span
        const float4* Xg4 = (const float4*)(X + (size_t)b0 * I_SZ);
        float4* L4 = (float4*)xls;
#pragma unroll
        for (int p = 0; p < (TB * I_SZ / 4) / 256; ++p)
            L4[tid + p * 256] = Xg4[tid + p * 256];
    }

    auto convert = [&](const float4& s4, const float4& t4, const float4& w4,
                       Coef& c) {
        const float* sa = (const float*)&s4;
        const float* ta = (const float*)&t4;
        const float* wa = (const float*)&w4;
#pragma unroll
        for (int cp = 0; cp < 2; ++cp) {
            const v2f r = { __builtin_amdgcn_rcpf(sa[2*cp]),
                            __builtin_amdgcn_rcpf(sa[2*cp+1]) };
            c.rk[cp]  = r * K;                                   // K/s
            c.tkn[cp] = -(v2f){ta[2*cp], ta[2*cp+1]} * c.rk[cp]; // -t*K/s
            c.wv[cp]  = (v2f){wa[2*cp], wa[2*cp+1]};             // raw w
        }
    };

    Coef cA, cB;
    convert(sR, tR, wR, cA);                   // coef for step 0
    {   const int pf = goff(1);                // load step 1 into raw
        sR = *(const float4*)(sr + pf);
        tR = *(const float4*)(tr + pf);
        wR = *(const float4*)(wr + pf);
    }
    __syncthreads();

    const float* xb = xls + sl * 4;

#pragma unroll 1
    for (int oi = 0; oi < OITER; ++oi) {
        v2f acc[TB];
#pragma unroll
        for (int j = 0; j < TB; ++j) acc[j] = (v2f)(0.0f);

#pragma unroll 1
        for (int k = 0; k < KITERS; k += 2) {
            const int g = oi * 8 + k;

#pragma unroll
            for (int ph = 0; ph < 2; ++ph) {
                // convert landed raw (step g+ph+1) into the OTHER coef set,
                // then refill raw with step g+ph+2 (in flight across compute)
                Coef& cCur = ph ? cB : cA;
                Coef& cNxt = ph ? cA : cB;
                convert(sR, tR, wR, cNxt);
                const int pf = goff(g + ph + 2);
                sR = *(const float4*)(sr + pf);
                tR = *(const float4*)(tr + pf);
                wR = *(const float4*)(wr + pf);

                const int i = (k + ph) * ISTEP;
#pragma unroll
                for (int j = 0; j < TB; ++j) {
                    const float4 xv = *(const float4*)(xb + j * I_SZ + i); // ds_read_b128
                    const float* xp = (const float*)&xv;
#pragma unroll
                    for (int cp = 0; cp < 2; ++cp) {
                        const v2f x2 = { xp[2*cp], xp[2*cp+1] };
                        const v2f u  = __builtin_elementwise_fma(x2, cCur.rk[cp],
                                                                 cCur.tkn[cp]);  // z*K
                        const v2f m  = u * (-u);                                 // -(z*K)^2
                        v2f e;
                        e.x = __builtin_amdgcn_exp2f(m.x);                       // exp(-z^2/2)
                        e.y = __builtin_amdgcn_exp2f(m.y);
                        const v2f y = u * cCur.wv[cp];                           // w*z*K
                        acc[j] = __builtin_elementwise_fma(-y, e, acc[j]);
                    }
                }
            }
        }

        // collapse pairs, reduce across the 32 i-split lanes
        float r[TB];
#pragma unroll
        for (int j = 0; j < TB; ++j) r[j] = acc[j].x + acc[j].y;
#pragma unroll
        for (int m = 1; m < SLN; m <<= 1)
#pragma unroll
            for (int j = 0; j < TB; ++j)
                r[j] += __shfl_xor(r[j], m, 64);

        if (sl < TB) {
            float v = 0.0f;
#pragma unroll
            for (int j = 0; j < TB; ++j)
                if (sl == j) v = r[j];
            // undo the z*K scale once here (wv kept raw): * 1/K
            Out[(size_t)(b0 + sl) * O_SZ + (obase + oi * 8)] =
                v * 1.17741002251547469101f;
        }
    }
}

extern "C" void kernel_launch(void* const* d_in, const int* in_sizes, int n_in,
                              void* d_out, int out_size, void* d_ws, size_t ws_size,
                              hipStream_t stream) {
    const float* x = (const float*)d_in[0];   // (B, I)
    const float* w = (const float*)d_in[1];   // (O, I)
    const float* s = (const float*)d_in[2];   // (O, I)
    const float* t = (const float*)d_in[3];   // (O, I)
    float* out = (float*)d_out;               // (B, O)

    dim3 grid(O_SZ / (8 * OITER), B_SZ / TB); // (32, 32) = 1024 blocks = 4/CU
    wavkan_dog_kernel<<<grid, 256, 0, stream>>>(x, w, s, t, out);
}